// Round 4
// baseline (19567.561 us; speedup 1.0000x reference)
//
#include <hip/hip_runtime.h>
#include <stdint.h>
#include <stddef.h>

typedef __bf16 bf16_t;
typedef bf16_t bf16x8 __attribute__((ext_vector_type(8)));
typedef bf16_t bf16x4 __attribute__((ext_vector_type(4)));
typedef float  f32x4  __attribute__((ext_vector_type(4)));

#define T_STEPS 2028
#define SEQ     2048
#define CIN     32
#define NGR     4      // batch groups (16 batches each)
#define MBB     16     // batch per group
#define CH      32     // chunk steps
#define NCH     64     // ceil(2028/32)
#define RING    4      // ring depth in chunks
#define XCH     (512*512)   // elements per ring slot: [512 stepbatch][512 cols]

// workspace layout (bytes); ~10 MB used
#define OFF_EFFW   0u          // bf16 [512][640]  (permuted gate rows)
#define OFF_BIAS   655360u     // f32  [4][512]    (permuted)
#define OFF_WHH    663552u     // bf16 [4][512][128] (permuted)
#define OFF_WIH    1187840u    // bf16 [3][512][128] (permuted, layers 1..3)
#define OFF_CNT    1613824u    // u32  counters, 64B-strided
#define OFF_XRING  1638400u    // bf16 [4 layers][NGR][RING][512][512]

__device__ __forceinline__ int endk(int k) {
  int e = (k + 1) * CH;
  return e > T_STEPS ? T_STEPS : e;
}

__device__ __forceinline__ void spin_ge(uint32_t* p, uint32_t tgt) {
  while (atomicAdd(p, 0u) < tgt) __builtin_amdgcn_s_sleep(2);
}
__device__ __forceinline__ void publish(uint32_t* p, uint32_t v) {
  __builtin_amdgcn_fence(__ATOMIC_RELEASE, "agent");
  atomicMax(p, v);
}

__device__ __forceinline__ float fsigm(float x) {
  return __builtin_amdgcn_rcpf(1.0f + __builtin_amdgcn_exp2f(x * -1.44269504089f));
}
__device__ __forceinline__ float ftanh(float x) {
  return 1.0f - 2.0f * __builtin_amdgcn_rcpf(1.0f + __builtin_amdgcn_exp2f(x * 2.88539008178f));
}

__device__ __forceinline__ bf16x8 ldg8(const bf16_t* p) { return *(const bf16x8*)p; }
__device__ __forceinline__ bf16x4 ldg4(const bf16_t* p) { return *(const bf16x4*)p; }

__device__ __forceinline__ bf16x8 ldg_cvt8(const float* p) {
  const f32x4 a = *(const f32x4*)p;
  const f32x4 b = *(const f32x4*)(p + 4);
  bf16x8 r;
  r[0] = (bf16_t)a[0]; r[1] = (bf16_t)a[1]; r[2] = (bf16_t)a[2]; r[3] = (bf16_t)a[3];
  r[4] = (bf16_t)b[0]; r[5] = (bf16_t)b[1]; r[6] = (bf16_t)b[2]; r[7] = (bf16_t)b[3];
  return r;
}

__device__ __forceinline__ bf16x4 pack4(f32x4 a) {
  bf16x4 v;
  v[0] = (bf16_t)a[0]; v[1] = (bf16_t)a[1]; v[2] = (bf16_t)a[2]; v[3] = (bf16_t)a[3];
  return v;
}

#define MFMA16(a, b, c) __builtin_amdgcn_mfma_f32_16x16x32_bf16((a), (b), (c), 0, 0, 0)

// permuted gate row p -> original row: gate = p&3 (i,f,g,o), j = p>>2; orig = gate*128 + j

// ---------------- prep: permute weights, biases, zero counters ----------------
__global__ void k_prep_misc(const float* __restrict__ w_hh0,
                            const float* __restrict__ w_ih_rest,
                            const float* __restrict__ w_hh_rest,
                            const float* __restrict__ b_ih_rest,
                            const float* __restrict__ b_hh_rest,
                            uint8_t* __restrict__ ws) {
  const int bid = blockIdx.x;          // 2048 blocks
  const int l = bid >> 9;              // 0..3
  const int p = bid & 511;
  const int orig = (p & 3) * 128 + (p >> 2);
  const int tid = threadIdx.x;         // 128 threads
  bf16_t* whh = (bf16_t*)(ws + OFF_WHH);
  bf16_t* wih = (bf16_t*)(ws + OFF_WIH);
  float* bias = (float*)(ws + OFF_BIAS);
  const float* src = (l == 0) ? (w_hh0 + orig * 128)
                              : (w_hh_rest + ((size_t)(l - 1) * 512 + orig) * 128);
  whh[((size_t)l * 512 + p) * 128 + tid] = (bf16_t)src[tid];
  if (l < 3)
    wih[((size_t)l * 512 + p) * 128 + tid] = (bf16_t)w_ih_rest[((size_t)l * 512 + orig) * 128 + tid];
  if (l >= 1 && tid == 0)
    bias[l * 512 + p] = b_ih_rest[(l - 1) * 512 + orig] + b_hh_rest[(l - 1) * 512 + orig];
  if (bid == 0) {
    uint32_t* cnt = (uint32_t*)(ws + OFF_CNT);
    for (int i = tid; i < 12 * 32 * 16; i += 128) cnt[i] = 0;
  }
}

// eff_w = w_ih0 @ proj_w (fused proj+layer0-input), eff_b -> bias[0]
__global__ void k_prep_effw(const float* __restrict__ proj_w,
                            const float* __restrict__ proj_b,
                            const float* __restrict__ w_ih0,
                            const float* __restrict__ b_ih0,
                            const float* __restrict__ b_hh0,
                            uint8_t* __restrict__ ws) {
  __shared__ float wr[320];
  const int p = blockIdx.x;            // 512 blocks
  const int orig = (p & 3) * 128 + (p >> 2);
  const int tid = threadIdx.x;         // 256 threads
  for (int i = tid; i < 320; i += 256) wr[i] = w_ih0[(size_t)orig * 320 + i];
  __syncthreads();
  bf16_t* effw = (bf16_t*)(ws + OFF_EFFW);
  for (int kk = tid; kk < 640; kk += 256) {
    float a = 0.f;
    for (int z = 0; z < 320; ++z) a += wr[z] * proj_w[(size_t)z * 640 + kk];
    effw[(size_t)p * 640 + kk] = (bf16_t)a;
  }
  if (tid == 0) {
    float a = 0.f;
    for (int z = 0; z < 320; ++z) a += wr[z] * proj_b[z];
    ((float*)(ws + OFF_BIAS))[p] = a + b_ih0[orig] + b_hh0[orig];
  }
}

// ---------------- persistent pipeline: 4 groups x 16 batches, 5 stages ----------------
// 512 threads = 8 waves. stage s = blockIdx.x>>2 : 0=conv, 1..4=recur l=s-1 ; g = blockIdx.x&3
// Batch-16 groups fill the MFMA B columns: per step per wave only 4Mt x 4Kt = 16 gate MFMAs
// (64 gate rows/wave), and the D tile hands each lane ALL FOUR gates of its unit in-register
// (rows mt*16+hi*4+r, col=batch ln) -> in-lane activations, no gate_buf LDS roundtrip.
// x_pre for layer l+1 is fused (same h B-operand); step trel stores x_pre[trel-1], a per-chunk
// flush covers the last step. xring layout [stepbatch=trel*16+b][col 512] so both conv and the
// fused producer emit bf16x4 (4 gates of one unit) vector stores that the consumer loads directly.
__global__ __launch_bounds__(512) void k_pipeline(const float* __restrict__ in,
                                                  const float* __restrict__ out_w,
                                                  const float* __restrict__ out_b,
                                                  float* __restrict__ out,
                                                  uint8_t* __restrict__ ws) {
  __shared__ __align__(16) bf16_t hfrag[2][4][64][8];  // [buf][kt][lane(q,ln)][8]: h[kt*32+q*8+e][b=ln]
  __shared__ float hfl[MBB][128];                      // final h (f32) for the fused output head

  const int s = blockIdx.x >> 2;       // 0..4
  const int g = blockIdx.x & 3;        // 0..3
  const int tid = threadIdx.x;
  const int wv = tid >> 6;             // wave 0..7
  const int lane = tid & 63;
  const int q = lane >> 4;             // 0..3  (hi)
  const int ln = lane & 15;            // 0..15

  uint32_t* cnt = (uint32_t*)(ws + OFF_CNT);
  bf16_t* xring = (bf16_t*)(ws + OFF_XRING);

  if (s == 0) {
    // ---- conv stage: x_pre0^T = eff_w @ windows^T -> ring0 ----
    const bf16_t* effw = (const bf16_t*)(ws + OFF_EFFW);
    uint32_t* my = cnt + (0 * NGR + g) * 16;
    uint32_t* guard = cnt + (1 * NGR + g) * 16;  // recur0 progress (ring free)
    for (int k = 0; k < NCH; ++k) {
      if (tid == 0 && k >= RING) spin_ge(guard, (uint32_t)endk(k - RING));
      __syncthreads();
      const int t0 = k * CH;
      const int tlen = (T_STEPS - t0 < CH) ? (T_STEPS - t0) : CH;
      bf16_t* xs = xring + (size_t)((0 * NGR + g) * RING + (k & 3)) * XCH;
      // wave's N tiles: nt = wv*4+j (N = stepbatch, one trel per tile). M blocked by 8.
      for (int mb = 0; mb < 4; ++mb) {
        f32x4 acc[8][4];
#pragma unroll
        for (int mi = 0; mi < 8; ++mi)
#pragma unroll
          for (int j = 0; j < 4; ++j) acc[mi][j] = (f32x4){0.f, 0.f, 0.f, 0.f};
#pragma unroll 4
        for (int kt = 0; kt < 20; ++kt) {        // kt == window offset
          bf16x8 bfr[4];
#pragma unroll
          for (int j = 0; j < 4; ++j) {
            int nt = wv * 4 + j;
            int tt = t0 + nt; if (tt > T_STEPS - 1) tt = T_STEPS - 1;
            bfr[j] = ldg_cvt8(in + (size_t)((g * MBB + ln) * SEQ + tt + kt) * CIN + q * 8);
          }
#pragma unroll
          for (int mi = 0; mi < 8; ++mi) {
            bf16x8 afr = ldg8(effw + (size_t)((mb * 8 + mi) * 16 + ln) * 640 + kt * 32 + q * 8);
#pragma unroll
            for (int j = 0; j < 4; ++j)
              acc[mi][j] = MFMA16(afr, bfr[j], acc[mi][j]);
          }
        }
        // store: rows (mb*8+mi)*16+q*4+r (4 gates of unit (mb*8+mi)*4+q), col stepbatch (wv*4+j)*16+ln
#pragma unroll
        for (int mi = 0; mi < 8; ++mi)
#pragma unroll
          for (int j = 0; j < 4; ++j) {
            int trel = wv * 4 + j;
            if (trel < tlen)
              *(bf16x4*)(xs + (size_t)(trel * 16 + ln) * 512 + (mb * 8 + mi) * 16 + q * 4) =
                  pack4(acc[mi][j]);
          }
      }
      __syncthreads();
      if (tid == 0) publish(my, (uint32_t)endk(k));
    }
  } else {
    // ---- recurrent stage, layer l (+ fused x_pre producer for layer l+1) ----
    const int l = s - 1;
    const bool has_next = (l < 3);
    const bf16_t* whh = (const bf16_t*)(ws + OFF_WHH) + (size_t)l * 512 * 128;
    bf16x8 wfr[4][4];                            // A = w_hh rows wv*64+mt*16+ln
#pragma unroll
    for (int mt = 0; mt < 4; ++mt)
#pragma unroll
      for (int kt = 0; kt < 4; ++kt)
        wfr[mt][kt] = ldg8(whh + (size_t)(wv * 64 + mt * 16 + ln) * 128 + kt * 32 + q * 8);
    bf16x8 wnx[4][4];                            // A = w_ih_{l+1} rows
    if (has_next) {
      const bf16_t* wih = (const bf16_t*)(ws + OFF_WIH) + (size_t)l * 512 * 128;
#pragma unroll
      for (int mt = 0; mt < 4; ++mt)
#pragma unroll
        for (int kt = 0; kt < 4; ++kt)
          wnx[mt][kt] = ldg8(wih + (size_t)(wv * 64 + mt * 16 + ln) * 128 + kt * 32 + q * 8);
    }
    // per-lane units: u = wv*16 + mt*4 + q, batch = ln
    f32x4 biasq[4];
    int hoff[4];                                 // element offset into hfrag[buf]
#pragma unroll
    for (int mt = 0; mt < 4; ++mt) {
      int u = wv * 16 + mt * 4 + q;
      biasq[mt] = *(const f32x4*)((const float*)(ws + OFF_BIAS) + l * 512 + 4 * u);
      hoff[mt] = ((u >> 5) * 64 + ((u >> 3) & 3) * 16 + ln) * 8 + (u & 7);
    }
    float cst[4] = {0.f, 0.f, 0.f, 0.f};
    {
      bf16_t* hz = &hfrag[0][0][0][0];
      for (int i = tid; i < 2 * 4 * 64 * 8; i += 512) hz[i] = (bf16_t)0.f;
    }
    __syncthreads();
    uint32_t* my = cnt + ((1 + l) * NGR + g) * 16;
    uint32_t* prod = cnt + (l * NGR + g) * 16;         // conv (l==0) or recur_{l-1}
    uint32_t* xguard = cnt + ((2 + l) * NGR + g) * 16; // recur_{l+1} progress (ring free)

    bf16_t* hb0 = &hfrag[0][0][0][0];
    bf16_t* hb1 = &hfrag[1][0][0][0];
    const bf16_t* hrd0 = &hfrag[0][0][lane][0];  // + kt*512 elements
    const bf16_t* hrd1 = &hfrag[1][0][lane][0];
    const int xcol = wv * 64;                    // this wave's column base (gate rows)

    for (int k = 0; k < NCH; ++k) {
      const int t0 = k * CH;
      const int tlen = (T_STEPS - t0 < CH) ? (T_STEPS - t0) : CH;
      if (tid == 0) {
        spin_ge(prod, (uint32_t)(t0 + tlen));
        if (has_next && k >= RING) spin_ge(xguard, (uint32_t)endk(k - RING));
        __builtin_amdgcn_fence(__ATOMIC_ACQUIRE, "agent");
      }
      __syncthreads();
      const bf16_t* xin = xring + (size_t)((l * NGR + g) * RING + (k & 3)) * XCH;
      bf16_t* xout = has_next
          ? xring + (size_t)(((l + 1) * NGR + g) * RING + (k & 3)) * XCH
          : nullptr;

      bf16x4 xq[4], xqn[4];
#pragma unroll
      for (int mt = 0; mt < 4; ++mt)
        xq[mt] = ldg4(xin + (size_t)(0 * 16 + ln) * 512 + xcol + mt * 16 + q * 4);

#pragma unroll 2
      for (int trel = 0; trel < tlen; ++trel) {
        const int buf = trel & 1;                // t0 even
        // prefetch next step's gate-pre (one full step of latency cover)
        if (trel + 1 < tlen) {
#pragma unroll
          for (int mt = 0; mt < 4; ++mt)
            xqn[mt] = ldg4(xin + (size_t)((trel + 1) * 16 + ln) * 512 + xcol + mt * 16 + q * 4);
        }
        const bf16_t* hr = buf ? hrd1 : hrd0;
        bf16x8 hk0 = *(const bf16x8*)(hr);
        bf16x8 hk1 = *(const bf16x8*)(hr + 512);
        bf16x8 hk2 = *(const bf16x8*)(hr + 1024);
        bf16x8 hk3 = *(const bf16x8*)(hr + 1536);
        f32x4 acc[4];
#pragma unroll
        for (int mt = 0; mt < 4; ++mt) acc[mt] = (f32x4){0.f, 0.f, 0.f, 0.f};
#pragma unroll
        for (int mt = 0; mt < 4; ++mt) acc[mt] = MFMA16(wfr[mt][0], hk0, acc[mt]);
#pragma unroll
        for (int mt = 0; mt < 4; ++mt) acc[mt] = MFMA16(wfr[mt][1], hk1, acc[mt]);
#pragma unroll
        for (int mt = 0; mt < 4; ++mt) acc[mt] = MFMA16(wfr[mt][2], hk2, acc[mt]);
#pragma unroll
        for (int mt = 0; mt < 4; ++mt) acc[mt] = MFMA16(wfr[mt][3], hk3, acc[mt]);
        // fused x_pre_{l+1}[trel-1] from the same h operand (h[trel-1])
        if (has_next && trel) {
          f32x4 a2[4];
#pragma unroll
          for (int mt = 0; mt < 4; ++mt) a2[mt] = (f32x4){0.f, 0.f, 0.f, 0.f};
#pragma unroll
          for (int mt = 0; mt < 4; ++mt) a2[mt] = MFMA16(wnx[mt][0], hk0, a2[mt]);
#pragma unroll
          for (int mt = 0; mt < 4; ++mt) a2[mt] = MFMA16(wnx[mt][1], hk1, a2[mt]);
#pragma unroll
          for (int mt = 0; mt < 4; ++mt) a2[mt] = MFMA16(wnx[mt][2], hk2, a2[mt]);
#pragma unroll
          for (int mt = 0; mt < 4; ++mt) a2[mt] = MFMA16(wnx[mt][3], hk3, a2[mt]);
#pragma unroll
          for (int mt = 0; mt < 4; ++mt)
            *(bf16x4*)(xout + (size_t)((trel - 1) * 16 + ln) * 512 + xcol + mt * 16 + q * 4) =
                pack4(a2[mt]);
        }
        // in-lane activations: 4 units (mt), batch ln
#pragma unroll
        for (int mt = 0; mt < 4; ++mt) {
          float p0 = acc[mt][0] + (float)xq[mt][0] + biasq[mt][0];
          float p1 = acc[mt][1] + (float)xq[mt][1] + biasq[mt][1];
          float p2 = acc[mt][2] + (float)xq[mt][2] + biasq[mt][2];
          float p3 = acc[mt][3] + (float)xq[mt][3] + biasq[mt][3];
          float gi = fsigm(p0), gf = fsigm(p1), gg = ftanh(p2), go = fsigm(p3);
          cst[mt] = gf * cst[mt] + gi * gg;
          float hv = go * ftanh(cst[mt]);
          (buf ? hb0 : hb1)[hoff[mt]] = (bf16_t)hv;      // h[trel] -> hfrag[buf^1]
          if (l == 3 && t0 + trel == T_STEPS - 1) hfl[ln][wv * 16 + mt * 4 + q] = hv;
        }
#pragma unroll
        for (int mt = 0; mt < 4; ++mt) xq[mt] = xqn[mt];
        asm volatile("s_waitcnt lgkmcnt(0)\n\ts_barrier" ::: "memory");
      }
      // ---- flush: x_pre_{l+1}[t0+tlen-1] from h[t0+tlen-1] (in hfrag[0], tlen even) ----
      if (has_next) {
        bf16x8 f0 = *(const bf16x8*)(hrd0);
        bf16x8 f1 = *(const bf16x8*)(hrd0 + 512);
        bf16x8 f2 = *(const bf16x8*)(hrd0 + 1024);
        bf16x8 f3 = *(const bf16x8*)(hrd0 + 1536);
        f32x4 a2[4];
#pragma unroll
        for (int mt = 0; mt < 4; ++mt) a2[mt] = (f32x4){0.f, 0.f, 0.f, 0.f};
#pragma unroll
        for (int mt = 0; mt < 4; ++mt) {
          a2[mt] = MFMA16(wnx[mt][0], f0, a2[mt]);
          a2[mt] = MFMA16(wnx[mt][1], f1, a2[mt]);
          a2[mt] = MFMA16(wnx[mt][2], f2, a2[mt]);
          a2[mt] = MFMA16(wnx[mt][3], f3, a2[mt]);
        }
#pragma unroll
        for (int mt = 0; mt < 4; ++mt)
          *(bf16x4*)(xout + (size_t)((tlen - 1) * 16 + ln) * 512 + xcol + mt * 16 + q * 4) =
              pack4(a2[mt]);
      }
      __syncthreads();   // drains vmcnt in every wave before publishing
      if (tid == 0) publish(my, (uint32_t)(t0 + tlen));
    }

    // ---- fused output head (layer-3 blocks only): out = h_fin @ out_w^T + out_b ----
    if (l == 3) {
      __syncthreads();                 // hfl visible to all waves
      for (int i = tid; i < MBB * 48; i += 512) {
        const int b_loc = i / 48, o = i % 48;
        const float* wrow = out_w + (size_t)o * 128;
        float a = out_b[o];
#pragma unroll 4
        for (int j = 0; j < 128; ++j) a += hfl[b_loc][j] * wrow[j];
        out[(size_t)(g * MBB + b_loc) * 48 + o] = a;
      }
    }
  }
}

extern "C" void kernel_launch(void* const* d_in, const int* in_sizes, int n_in,
                              void* d_out, int out_size, void* d_ws, size_t ws_size,
                              hipStream_t stream) {
  (void)in_sizes; (void)n_in; (void)out_size; (void)ws_size;
  const float* inputs    = (const float*)d_in[0];
  const float* proj_w    = (const float*)d_in[4];
  const float* proj_b    = (const float*)d_in[5];
  const float* w_ih0     = (const float*)d_in[6];
  const float* w_hh0     = (const float*)d_in[7];
  const float* b_ih0     = (const float*)d_in[8];
  const float* b_hh0     = (const float*)d_in[9];
  const float* w_ih_rest = (const float*)d_in[10];
  const float* w_hh_rest = (const float*)d_in[11];
  const float* b_ih_rest = (const float*)d_in[12];
  const float* b_hh_rest = (const float*)d_in[13];
  const float* out_w     = (const float*)d_in[14];
  const float* out_b     = (const float*)d_in[15];
  uint8_t* ws = (uint8_t*)d_ws;
  float* out = (float*)d_out;

  k_prep_misc<<<dim3(2048), dim3(128), 0, stream>>>(w_hh0, w_ih_rest, w_hh_rest,
                                                    b_ih_rest, b_hh_rest, ws);
  k_prep_effw<<<dim3(512), dim3(256), 0, stream>>>(proj_w, proj_b, w_ih0, b_ih0, b_hh0, ws);
  k_pipeline<<<dim3(20), dim3(512), 0, stream>>>(inputs, out_w, out_b, out, ws);
}

// Round 5
// 6451.579 us; speedup vs baseline: 3.0330x; 3.0330x over previous
//
#include <hip/hip_runtime.h>
#include <stdint.h>
#include <stddef.h>

typedef __bf16 bf16_t;
typedef bf16_t bf16x8 __attribute__((ext_vector_type(8)));
typedef bf16_t bf16x4 __attribute__((ext_vector_type(4)));
typedef float  f32x4  __attribute__((ext_vector_type(4)));

#define T_STEPS 2028
#define SEQ     2048
#define CIN     32
#define NGR     4      // batch groups (16 batches each)
#define MBB     16     // batch per group
#define CH      32     // chunk steps
#define NCH     64     // ceil(2028/32)
#define RING    4      // ring depth in chunks
#define XCH     (512*512)   // elements per ring slot: [512 stepbatch][512 cols]

// workspace layout (bytes); ~35 MB
#define OFF_EFFW   0u          // bf16 [512][640]  (permuted gate rows)
#define OFF_BIAS   655360u     // f32  [4][512]    (permuted)
#define OFF_WHH    663552u     // bf16 [4][512][128] (permuted)
#define OFF_WIH    1187840u    // bf16 [3][512][128] (permuted, layers 1..3)
#define OFF_CNT    1613824u    // u32  counters, 64B-strided
#define OFF_XRING  1638400u    // bf16 [4 layers][NGR][RING][512][512]

// permuted gate row p -> original LSTM row. Chosen so that in the recur stage,
// lane (q,ln) of wave w holds ALL FOUR gates of unit u = w*32 + q*8 + mt in acc[mt],
// and its 8 h outputs (mt=0..7) pack contiguously into the MFMA B-fragment slot
// hfrag[kt=w][lane q*16+ln][e=mt]  ->  ONE ds_write_b128 per lane per step.
__device__ __host__ __forceinline__ int orig_row(int p) {
  return (p & 3) * 128 + ((p >> 7) * 32 + ((p >> 2) & 3) * 8 + ((p >> 4) & 7));
}

__device__ __forceinline__ int endk(int k) {
  int e = (k + 1) * CH;
  return e > T_STEPS ? T_STEPS : e;
}

__device__ __forceinline__ void spin_ge(uint32_t* p, uint32_t tgt) {
  while (atomicAdd(p, 0u) < tgt) __builtin_amdgcn_s_sleep(2);
}
__device__ __forceinline__ void publish(uint32_t* p, uint32_t v) {
  __builtin_amdgcn_fence(__ATOMIC_RELEASE, "agent");
  atomicMax(p, v);
}

__device__ __forceinline__ float fsigm(float x) {
  return __builtin_amdgcn_rcpf(1.0f + __builtin_amdgcn_exp2f(x * -1.44269504089f));
}
__device__ __forceinline__ float ftanh(float x) {
  return 1.0f - 2.0f * __builtin_amdgcn_rcpf(1.0f + __builtin_amdgcn_exp2f(x * 2.88539008178f));
}

__device__ __forceinline__ bf16x8 ldg8(const bf16_t* p) { return *(const bf16x8*)p; }
__device__ __forceinline__ bf16x4 ldg4(const bf16_t* p) { return *(const bf16x4*)p; }

__device__ __forceinline__ bf16x8 ldg_cvt8(const float* p) {
  const f32x4 a = *(const f32x4*)p;
  const f32x4 b = *(const f32x4*)(p + 4);
  bf16x8 r;
  r[0] = (bf16_t)a[0]; r[1] = (bf16_t)a[1]; r[2] = (bf16_t)a[2]; r[3] = (bf16_t)a[3];
  r[4] = (bf16_t)b[0]; r[5] = (bf16_t)b[1]; r[6] = (bf16_t)b[2]; r[7] = (bf16_t)b[3];
  return r;
}

__device__ __forceinline__ bf16x4 pack4(f32x4 a) {
  bf16x4 v;
  v[0] = (bf16_t)a[0]; v[1] = (bf16_t)a[1]; v[2] = (bf16_t)a[2]; v[3] = (bf16_t)a[3];
  return v;
}

#define MFMA16(a, b, c) __builtin_amdgcn_mfma_f32_16x16x32_bf16((a), (b), (c), 0, 0, 0)

// ---------------- prep: permute weights, biases, zero counters ----------------
__global__ void k_prep_misc(const float* __restrict__ w_hh0,
                            const float* __restrict__ w_ih_rest,
                            const float* __restrict__ w_hh_rest,
                            const float* __restrict__ b_ih_rest,
                            const float* __restrict__ b_hh_rest,
                            uint8_t* __restrict__ ws) {
  const int bid = blockIdx.x;          // 2048 blocks
  const int l = bid >> 9;              // 0..3
  const int p = bid & 511;
  const int orig = orig_row(p);
  const int tid = threadIdx.x;         // 128 threads
  bf16_t* whh = (bf16_t*)(ws + OFF_WHH);
  bf16_t* wih = (bf16_t*)(ws + OFF_WIH);
  float* bias = (float*)(ws + OFF_BIAS);
  const float* src = (l == 0) ? (w_hh0 + orig * 128)
                              : (w_hh_rest + ((size_t)(l - 1) * 512 + orig) * 128);
  whh[((size_t)l * 512 + p) * 128 + tid] = (bf16_t)src[tid];
  if (l < 3)
    wih[((size_t)l * 512 + p) * 128 + tid] = (bf16_t)w_ih_rest[((size_t)l * 512 + orig) * 128 + tid];
  if (l >= 1 && tid == 0)
    bias[l * 512 + p] = b_ih_rest[(l - 1) * 512 + orig] + b_hh_rest[(l - 1) * 512 + orig];
  if (bid == 0) {
    uint32_t* cnt = (uint32_t*)(ws + OFF_CNT);
    for (int i = tid; i < 12 * 32 * 16; i += 128) cnt[i] = 0;
  }
}

// eff_w = w_ih0 @ proj_w (fused proj+layer0-input), eff_b -> bias[0]
__global__ void k_prep_effw(const float* __restrict__ proj_w,
                            const float* __restrict__ proj_b,
                            const float* __restrict__ w_ih0,
                            const float* __restrict__ b_ih0,
                            const float* __restrict__ b_hh0,
                            uint8_t* __restrict__ ws) {
  __shared__ float wr[320];
  const int p = blockIdx.x;            // 512 blocks
  const int orig = orig_row(p);
  const int tid = threadIdx.x;         // 256 threads
  for (int i = tid; i < 320; i += 256) wr[i] = w_ih0[(size_t)orig * 320 + i];
  __syncthreads();
  bf16_t* effw = (bf16_t*)(ws + OFF_EFFW);
  for (int kk = tid; kk < 640; kk += 256) {
    float a = 0.f;
    for (int z = 0; z < 320; ++z) a += wr[z] * proj_w[(size_t)z * 640 + kk];
    effw[(size_t)p * 640 + kk] = (bf16_t)a;
  }
  if (tid == 0) {
    float a = 0.f;
    for (int z = 0; z < 320; ++z) a += wr[z] * proj_b[z];
    ((float*)(ws + OFF_BIAS))[p] = a + b_ih0[orig] + b_hh0[orig];
  }
}

// ---------------- persistent pipeline: 4 groups x 16 batches ----------------
// 32 blocks x 256 threads (4 waves, 1 wave/SIMD -> full 512-reg budget; the 512-thread
// variants get VGPR-capped to 128 and spill the resident weights -- rounds 3/4 failure).
// blocks 0..15 : conv sub-block  (g = b&3, mq = b>>2 owns gate rows mq*128..mq*128+127)
// blocks 16..31: recur layer l = (b-16)>>2, group g = b&3, + fused x_pre for layer l+1.
// counters: conv -> id mq (0..3); recur_l -> id 4+l.
__global__ __launch_bounds__(256, 1) void k_pipeline(const float* __restrict__ in,
                                                     const float* __restrict__ out_w,
                                                     const float* __restrict__ out_b,
                                                     float* __restrict__ out,
                                                     uint8_t* __restrict__ ws) {
  __shared__ __align__(16) bf16_t hfrag[2][4][64][8];  // [buf][kt][lane q*16+ln][e]
  __shared__ float hfl[MBB][128];                      // final h (f32) for output head

  const int b = blockIdx.x;
  const int tid = threadIdx.x;
  const int w = tid >> 6;              // wave 0..3
  const int lane = tid & 63;
  const int q = lane >> 4;             // 0..3
  const int ln = lane & 15;            // 0..15 (= batch in recur / conv B-cols)

  uint32_t* cnt = (uint32_t*)(ws + OFF_CNT);
  bf16_t* xring = (bf16_t*)(ws + OFF_XRING);

  if (b < 16) {
    // ---- conv sub-block: gate rows mq*128.. for group g -> ring0 ----
    const int mq = b >> 2, g = b & 3;
    const bf16_t* effw = (const bf16_t*)(ws + OFF_EFFW);
    uint32_t* my = cnt + (mq * NGR + g) * 16;
    uint32_t* guard = cnt + ((4 + 0) * NGR + g) * 16;   // recur0 progress (ring free)
    for (int k = 0; k < NCH; ++k) {
      if (tid == 0 && k >= RING) spin_ge(guard, (uint32_t)endk(k - RING));
      __syncthreads();
      const int t0 = k * CH;
      bf16_t* xs = xring + (size_t)((0 * NGR + g) * RING + (k & 3)) * XCH;
      for (int mb = 0; mb < 2; ++mb) {
        f32x4 acc[4][8];
#pragma unroll
        for (int mi = 0; mi < 4; ++mi)
#pragma unroll
          for (int j = 0; j < 8; ++j) acc[mi][j] = (f32x4){0.f, 0.f, 0.f, 0.f};
#pragma unroll 4
        for (int kt = 0; kt < 20; ++kt) {        // kt == window offset
          bf16x8 bfr[8];
#pragma unroll
          for (int j = 0; j < 8; ++j) {
            int tt = t0 + w * 8 + j;
            if (tt > T_STEPS - 1) tt = T_STEPS - 1;
            bfr[j] = ldg_cvt8(in + (size_t)((g * MBB + ln) * SEQ + tt + kt) * CIN + q * 8);
          }
#pragma unroll
          for (int mi = 0; mi < 4; ++mi) {
            bf16x8 afr = ldg8(effw + (size_t)(mq * 128 + (mb * 4 + mi) * 16 + ln) * 640
                              + kt * 32 + q * 8);
#pragma unroll
            for (int j = 0; j < 8; ++j)
              acc[mi][j] = MFMA16(afr, bfr[j], acc[mi][j]);
          }
        }
#pragma unroll
        for (int mi = 0; mi < 4; ++mi)
#pragma unroll
          for (int j = 0; j < 8; ++j)
            *(bf16x4*)(xs + (size_t)((w * 8 + j) * 16 + ln) * 512
                       + mq * 128 + (mb * 4 + mi) * 16 + q * 4) = pack4(acc[mi][j]);
      }
      __syncthreads();
      if (tid == 0) publish(my, (uint32_t)endk(k));
    }
  } else {
    // ---- recurrent stage, layer l (+ fused x_pre producer for layer l+1) ----
    const int l = (b - 16) >> 2, g = b & 3;
    const bool has_next = (l < 3);
    const bf16_t* whh = (const bf16_t*)(ws + OFF_WHH) + (size_t)l * 512 * 128;
    bf16x8 wfr[8][4];                            // A = w_hh rows w*128+mt*16+ln
#pragma unroll
    for (int mt = 0; mt < 8; ++mt)
#pragma unroll
      for (int kt = 0; kt < 4; ++kt)
        wfr[mt][kt] = ldg8(whh + (size_t)(w * 128 + mt * 16 + ln) * 128 + kt * 32 + q * 8);
    bf16x8 wnx[8][4];                            // A = w_ih_{l+1} rows
    if (has_next) {
      const bf16_t* wih = (const bf16_t*)(ws + OFF_WIH) + (size_t)l * 512 * 128;
#pragma unroll
      for (int mt = 0; mt < 8; ++mt)
#pragma unroll
        for (int kt = 0; kt < 4; ++kt)
          wnx[mt][kt] = ldg8(wih + (size_t)(w * 128 + mt * 16 + ln) * 128 + kt * 32 + q * 8);
    }
    // lane (q,ln): acc[mt] holds gates i,f,g,o of unit u = w*32+q*8+mt, batch ln
    f32x4 biasq[8];
#pragma unroll
    for (int mt = 0; mt < 8; ++mt)
      biasq[mt] = *(const f32x4*)((const float*)(ws + OFF_BIAS) + l * 512
                                  + w * 128 + mt * 16 + q * 4);
    float cst[8];
#pragma unroll
    for (int mt = 0; mt < 8; ++mt) cst[mt] = 0.f;
    {
      bf16_t* hz = &hfrag[0][0][0][0];
      for (int i = tid; i < 2 * 4 * 64 * 8; i += 256) hz[i] = (bf16_t)0.f;
    }
    __syncthreads();
    uint32_t* my = cnt + ((4 + l) * NGR + g) * 16;
    uint32_t* prod = cnt + ((3 + l) * NGR + g) * 16;   // recur_{l-1} (l>=1)
    uint32_t* xguard = cnt + ((5 + l) * NGR + g) * 16; // recur_{l+1} progress (ring free)

    bf16_t* hw = &hfrag[0][w][q * 16 + ln][0];         // +2048 elems for buf 1

    for (int k = 0; k < NCH; ++k) {
      const int t0 = k * CH;
      const int tlen = (T_STEPS - t0 < CH) ? (T_STEPS - t0) : CH;
      if (tid == 0) {
        if (l == 0) {
          for (int mq = 0; mq < 4; ++mq)
            spin_ge(cnt + (mq * NGR + g) * 16, (uint32_t)(t0 + tlen));
        } else {
          spin_ge(prod, (uint32_t)(t0 + tlen));
        }
        if (has_next && k >= RING) spin_ge(xguard, (uint32_t)endk(k - RING));
        __builtin_amdgcn_fence(__ATOMIC_ACQUIRE, "agent");
      }
      __syncthreads();
      const bf16_t* xin = xring + (size_t)((l * NGR + g) * RING + (k & 3)) * XCH;
      bf16_t* xout = xring + (size_t)(((has_next ? l + 1 : l) * NGR + g) * RING + (k & 3)) * XCH;

      bf16x4 xq[8], xqn[8];
#pragma unroll
      for (int mt = 0; mt < 8; ++mt)
        xq[mt] = ldg4(xin + (size_t)(0 * 16 + ln) * 512 + w * 128 + mt * 16 + q * 4);

#pragma unroll 2
      for (int trel = 0; trel < tlen; ++trel) {
        const int buf = trel & 1;                // t0 even -> parity continuous
        if (trel + 1 < tlen) {
#pragma unroll
          for (int mt = 0; mt < 8; ++mt)
            xqn[mt] = ldg4(xin + (size_t)((trel + 1) * 16 + ln) * 512 + w * 128 + mt * 16 + q * 4);
        }
        const bf16_t* hr = &hfrag[buf][0][q * 16 + ln][0];   // +kt*512 per k-slice
        bf16x8 hk0 = *(const bf16x8*)(hr);
        bf16x8 hk1 = *(const bf16x8*)(hr + 512);
        bf16x8 hk2 = *(const bf16x8*)(hr + 1024);
        bf16x8 hk3 = *(const bf16x8*)(hr + 1536);
        f32x4 acc[8];
#pragma unroll
        for (int mt = 0; mt < 8; ++mt) acc[mt] = (f32x4){0.f, 0.f, 0.f, 0.f};
#pragma unroll
        for (int mt = 0; mt < 8; ++mt) acc[mt] = MFMA16(wfr[mt][0], hk0, acc[mt]);
#pragma unroll
        for (int mt = 0; mt < 8; ++mt) acc[mt] = MFMA16(wfr[mt][1], hk1, acc[mt]);
#pragma unroll
        for (int mt = 0; mt < 8; ++mt) acc[mt] = MFMA16(wfr[mt][2], hk2, acc[mt]);
#pragma unroll
        for (int mt = 0; mt < 8; ++mt) acc[mt] = MFMA16(wfr[mt][3], hk3, acc[mt]);
        // fused x_pre_{l+1}[trel-1] from the same h operand (h[trel-1])
        if (has_next && trel) {
          f32x4 a2[8];
#pragma unroll
          for (int mt = 0; mt < 8; ++mt) a2[mt] = (f32x4){0.f, 0.f, 0.f, 0.f};
#pragma unroll
          for (int mt = 0; mt < 8; ++mt) a2[mt] = MFMA16(wnx[mt][0], hk0, a2[mt]);
#pragma unroll
          for (int mt = 0; mt < 8; ++mt) a2[mt] = MFMA16(wnx[mt][1], hk1, a2[mt]);
#pragma unroll
          for (int mt = 0; mt < 8; ++mt) a2[mt] = MFMA16(wnx[mt][2], hk2, a2[mt]);
#pragma unroll
          for (int mt = 0; mt < 8; ++mt) a2[mt] = MFMA16(wnx[mt][3], hk3, a2[mt]);
#pragma unroll
          for (int mt = 0; mt < 8; ++mt)
            *(bf16x4*)(xout + (size_t)((trel - 1) * 16 + ln) * 512
                       + w * 128 + mt * 16 + q * 4) = pack4(a2[mt]);
        }
        // in-lane activations: 8 units (mt) x batch ln; pack h into one b128 write
        bf16x8 hnew;
#pragma unroll
        for (int mt = 0; mt < 8; ++mt) {
          float p0 = acc[mt][0] + (float)xq[mt][0] + biasq[mt][0];
          float p1 = acc[mt][1] + (float)xq[mt][1] + biasq[mt][1];
          float p2 = acc[mt][2] + (float)xq[mt][2] + biasq[mt][2];
          float p3 = acc[mt][3] + (float)xq[mt][3] + biasq[mt][3];
          float gi = fsigm(p0), gf = fsigm(p1), gg = ftanh(p2), go = fsigm(p3);
          cst[mt] = gf * cst[mt] + gi * gg;
          float hv = go * ftanh(cst[mt]);
          hnew[mt] = (bf16_t)hv;
          if (l == 3 && t0 + trel == T_STEPS - 1) hfl[ln][w * 32 + q * 8 + mt] = hv;
        }
        *(bf16x8*)(hw + (buf ^ 1) * 2048) = hnew;          // hfrag[buf^1][w][q*16+ln][:]
#pragma unroll
        for (int mt = 0; mt < 8; ++mt) xq[mt] = xqn[mt];
        asm volatile("s_waitcnt lgkmcnt(0)\n\ts_barrier" ::: "memory");
      }
      // ---- flush: x_pre_{l+1}[t0+tlen-1] from h[t0+tlen-1] (in hfrag[0], tlen even) ----
      if (has_next) {
        const bf16_t* hr = &hfrag[0][0][q * 16 + ln][0];
        bf16x8 f0 = *(const bf16x8*)(hr);
        bf16x8 f1 = *(const bf16x8*)(hr + 512);
        bf16x8 f2 = *(const bf16x8*)(hr + 1024);
        bf16x8 f3 = *(const bf16x8*)(hr + 1536);
        f32x4 a2[8];
#pragma unroll
        for (int mt = 0; mt < 8; ++mt) a2[mt] = (f32x4){0.f, 0.f, 0.f, 0.f};
#pragma unroll
        for (int mt = 0; mt < 8; ++mt) {
          a2[mt] = MFMA16(wnx[mt][0], f0, a2[mt]);
          a2[mt] = MFMA16(wnx[mt][1], f1, a2[mt]);
          a2[mt] = MFMA16(wnx[mt][2], f2, a2[mt]);
          a2[mt] = MFMA16(wnx[mt][3], f3, a2[mt]);
        }
#pragma unroll
        for (int mt = 0; mt < 8; ++mt)
          *(bf16x4*)(xout + (size_t)((tlen - 1) * 16 + ln) * 512
                     + w * 128 + mt * 16 + q * 4) = pack4(a2[mt]);
      }
      __syncthreads();   // drains vmcnt in every wave before publishing
      if (tid == 0) publish(my, (uint32_t)(t0 + tlen));
    }

    // ---- fused output head (layer-3 blocks only): out = h_fin @ out_w^T + out_b ----
    if (l == 3) {
      __syncthreads();                 // hfl visible to all waves
      for (int i = tid; i < MBB * 48; i += 256) {
        const int b_loc = i / 48, o = i % 48;
        const float* wrow = out_w + (size_t)o * 128;
        float a = out_b[o];
#pragma unroll 4
        for (int j = 0; j < 128; ++j) a += hfl[b_loc][j] * wrow[j];
        out[(size_t)(g * MBB + b_loc) * 48 + o] = a;
      }
    }
  }
}

extern "C" void kernel_launch(void* const* d_in, const int* in_sizes, int n_in,
                              void* d_out, int out_size, void* d_ws, size_t ws_size,
                              hipStream_t stream) {
  (void)in_sizes; (void)n_in; (void)out_size; (void)ws_size;
  const float* inputs    = (const float*)d_in[0];
  const float* proj_w    = (const float*)d_in[4];
  const float* proj_b    = (const float*)d_in[5];
  const float* w_ih0     = (const float*)d_in[6];
  const float* w_hh0     = (const float*)d_in[7];
  const float* b_ih0     = (const float*)d_in[8];
  const float* b_hh0     = (const float*)d_in[9];
  const float* w_ih_rest = (const float*)d_in[10];
  const float* w_hh_rest = (const float*)d_in[11];
  const float* b_ih_rest = (const float*)d_in[12];
  const float* b_hh_rest = (const float*)d_in[13];
  const float* out_w     = (const float*)d_in[14];
  const float* out_b     = (const float*)d_in[15];
  uint8_t* ws = (uint8_t*)d_ws;
  float* out = (float*)d_out;

  k_prep_misc<<<dim3(2048), dim3(128), 0, stream>>>(w_hh0, w_ih_rest, w_hh_rest,
                                                    b_ih_rest, b_hh_rest, ws);
  k_prep_effw<<<dim3(512), dim3(256), 0, stream>>>(proj_w, proj_b, w_ih0, b_ih0, b_hh0, ws);
  k_pipeline<<<dim3(32), dim3(256), 0, stream>>>(inputs, out_w, out_b, out, ws);
}